// Round 2
// baseline (2700.413 us; speedup 1.0000x reference)
//
#include <hip/hip_runtime.h>
#include <math.h>

#define Bv 4
#define Sv 2048
#define Dv 1024
#define Hv 16
#define HD 64
#define NEGV (-1.0e9f)

// ---------------------------------------------------------------------------
// Tiled fp32 GEMM: C = X[MxK] @ W[KxN] + bias[N]
// PERM=0: C row-major [M,N].  PERM=1: write to [H,S,64] (per-batch q/k/v).
// Tile 64x64, BK=16, 256 threads, 4x4 accum per thread.
// ---------------------------------------------------------------------------
template <int PERM>
__global__ __launch_bounds__(256) void gemm_k(const float* __restrict__ X,
                                              const float* __restrict__ W,
                                              const float* __restrict__ bias,
                                              float* __restrict__ C,
                                              int M, int N, int K) {
    const int BM = 64, BN = 64, BK = 16;
    __shared__ __align__(16) float Xs[BK][BM + 4];  // [k][m]
    __shared__ __align__(16) float Ws[BK][BN + 4];  // [k][n]

    const int t = threadIdx.x;        // 0..255
    const int tx = t & 15, ty = t >> 4;
    const int m0 = blockIdx.y * BM, n0 = blockIdx.x * BN;

    float acc[4][4] = {};

    for (int k0 = 0; k0 < K; k0 += BK) {
        // Load X tile transposed into LDS: Xs[k][m]
        {
            const int k = t & 15;
            const int mb = t >> 4;
            #pragma unroll
            for (int p = 0; p < 4; ++p) {
                const int m = mb + 16 * p;
                Xs[k][m] = X[(size_t)(m0 + m) * K + k0 + k];
            }
        }
        // Load W tile: Ws[k][n]
        {
            const int n = t & 63;
            const int kb = t >> 6;  // 0..3
            #pragma unroll
            for (int p = 0; p < 4; ++p) {
                const int k = kb + 4 * p;
                Ws[k][n] = W[(size_t)(k0 + k) * N + n0 + n];
            }
        }
        __syncthreads();

        #pragma unroll
        for (int k = 0; k < BK; ++k) {
            const float4 xa = *reinterpret_cast<const float4*>(&Xs[k][ty * 4]);
            const float4 wb = *reinterpret_cast<const float4*>(&Ws[k][tx * 4]);
            const float xr[4] = {xa.x, xa.y, xa.z, xa.w};
            const float wc[4] = {wb.x, wb.y, wb.z, wb.w};
            #pragma unroll
            for (int i = 0; i < 4; ++i)
                #pragma unroll
                for (int j = 0; j < 4; ++j)
                    acc[i][j] += xr[i] * wc[j];
        }
        __syncthreads();
    }

    // Epilogue: bias + store
    #pragma unroll
    for (int i = 0; i < 4; ++i) {
        const int m = m0 + ty * 4 + i;   // = s (PERM=1, M==Sv so b==0)
        #pragma unroll
        for (int j = 0; j < 4; ++j) {
            const int n = n0 + tx * 4 + j;
            const float v = acc[i][j] + bias[n];
            if (PERM == 0) {
                C[(size_t)m * N + n] = v;
            } else {
                // n = h*64 + d  ->  [H,S,64]
                const int h = n >> 6, d = n & 63;
                C[(((size_t)h * Sv + m) << 6) + d] = v;
            }
        }
    }
}

// ---------------------------------------------------------------------------
// Flash-style attention, fp32, one batch. Grid: (S/64, H). Block: 256.
// Q,K,V in [H,S,64]. mask: int[S] for this batch (1 = masked out).
// Output: [S, H*64].
// Thread t: q-row r = t>>2, 16-wide column group cg = t&3. The 4 lanes of a
// row are contiguous in one wave -> width-4 shuffles share m/l/P exactly.
// LDS: 3 x 64x68 fp32 = 52.2 KB (padding +4 keeps conflicts <=2-way = free).
// ---------------------------------------------------------------------------
__global__ __launch_bounds__(256) void attn_k(const float* __restrict__ Q,
                                              const float* __restrict__ Kg,
                                              const float* __restrict__ V,
                                              const int* __restrict__ mask,
                                              float* __restrict__ O) {
    __shared__ __align__(16) float Ql[64][68];  // [r][d]
    __shared__ __align__(16) float Kl[64][68];  // [d][kk]  (transposed)
    __shared__ __align__(16) float Vl[64][68];  // [kk][d]
    __shared__ float Mk[64];                    // additive mask per key

    const int t = threadIdx.x;
    const int q0 = blockIdx.x * 64;
    const int h = blockIdx.y;

    const size_t baseQ = ((size_t)h * Sv + q0) * 64;
    const size_t baseKV = (size_t)h * Sv * 64;

    // Load Q tile: Ql[r][d]
    {
        const int dd = (t & 15) * 4;
        const int rb = t >> 4;
        #pragma unroll
        for (int p = 0; p < 4; ++p) {
            const int rr = rb + 16 * p;
            const float4 qv =
                *reinterpret_cast<const float4*>(&Q[baseQ + (size_t)rr * 64 + dd]);
            *reinterpret_cast<float4*>(&Ql[rr][dd]) = qv;
        }
    }

    const int r = t >> 2;   // q-row 0..63
    const int cg = t & 3;   // 16-wide column group

    float m_i = -INFINITY, l_i = 0.0f;
    float Oacc[16];
    #pragma unroll
    for (int j = 0; j < 16; ++j) Oacc[j] = 0.0f;

    for (int k0 = 0; k0 < Sv; k0 += 64) {
        __syncthreads();  // protect LDS (incl. Ql on first iter) before overwrite

        // Load K tile (transposed -> Kl[d][kk]), V tile (Vl[kk][d]), mask
        {
            const int dd = (t & 15) * 4;
            const int kb = t >> 4;
            #pragma unroll
            for (int p = 0; p < 4; ++p) {
                const int kk = kb + 16 * p;
                const float4 kv = *reinterpret_cast<const float4*>(
                    &Kg[baseKV + (size_t)(k0 + kk) * 64 + dd]);
                Kl[dd + 0][kk] = kv.x;
                Kl[dd + 1][kk] = kv.y;
                Kl[dd + 2][kk] = kv.z;
                Kl[dd + 3][kk] = kv.w;
                const float4 vv = *reinterpret_cast<const float4*>(
                    &V[baseKV + (size_t)(k0 + kk) * 64 + dd]);
                *reinterpret_cast<float4*>(&Vl[kk][dd]) = vv;
            }
        }
        if (t < 64) Mk[t] = NEGV * (float)mask[k0 + t];
        __syncthreads();

        // Scores for 16 keys: kk = cg*16 + j
        float s[16];
        #pragma unroll
        for (int j = 0; j < 16; ++j) s[j] = 0.0f;
        for (int d4 = 0; d4 < 16; ++d4) {
            const float4 q4 = *reinterpret_cast<const float4*>(&Ql[r][d4 * 4]);
            const float qd[4] = {q4.x, q4.y, q4.z, q4.w};
            #pragma unroll
            for (int dd = 0; dd < 4; ++dd) {
                const int d = d4 * 4 + dd;
                const float4* kp = reinterpret_cast<const float4*>(&Kl[d][cg * 16]);
                #pragma unroll
                for (int j4 = 0; j4 < 4; ++j4) {
                    const float4 kv = kp[j4];
                    s[j4 * 4 + 0] += qd[dd] * kv.x;
                    s[j4 * 4 + 1] += qd[dd] * kv.y;
                    s[j4 * 4 + 2] += qd[dd] * kv.z;
                    s[j4 * 4 + 3] += qd[dd] * kv.w;
                }
            }
        }

        float mloc = -INFINITY;
        #pragma unroll
        for (int j = 0; j < 16; ++j) {
            s[j] = s[j] * 0.125f + Mk[cg * 16 + j];
            mloc = fmaxf(mloc, s[j]);
        }
        // Max over the 4 lanes sharing row r (contiguous lanes, same wave)
        mloc = fmaxf(mloc, __shfl_xor(mloc, 1, 4));
        mloc = fmaxf(mloc, __shfl_xor(mloc, 2, 4));
        const float mnew = fmaxf(m_i, mloc);
        const float alpha = __expf(m_i - mnew);

        float p[16];
        float rs = 0.0f;
        #pragma unroll
        for (int j = 0; j < 16; ++j) {
            p[j] = __expf(s[j] - mnew);
            rs += p[j];
        }
        rs += __shfl_xor(rs, 1, 4);
        rs += __shfl_xor(rs, 2, 4);
        l_i = l_i * alpha + rs;
        m_i = mnew;

        // PV: share P across the 4 row-lanes via width-4 shuffles (no LDS).
        #pragma unroll
        for (int j = 0; j < 16; ++j) Oacc[j] *= alpha;
        #pragma unroll
        for (int src = 0; src < 4; ++src) {
            #pragma unroll
            for (int j = 0; j < 16; ++j) {
                const float pv = __shfl(p[j], src, 4);
                const int kk = src * 16 + j;
                const float4* vp = reinterpret_cast<const float4*>(&Vl[kk][cg * 16]);
                #pragma unroll
                for (int j4 = 0; j4 < 4; ++j4) {
                    const float4 vv = vp[j4];
                    Oacc[j4 * 4 + 0] += pv * vv.x;
                    Oacc[j4 * 4 + 1] += pv * vv.y;
                    Oacc[j4 * 4 + 2] += pv * vv.z;
                    Oacc[j4 * 4 + 3] += pv * vv.w;
                }
            }
        }
    }

    // Write O row: [S, H*64]
    const float inv = 1.0f / l_i;
    const size_t obase = ((size_t)(q0 + r)) * (size_t)(Hv * HD) + h * HD + cg * 16;
    #pragma unroll
    for (int j4 = 0; j4 < 4; ++j4) {
        float4 ov;
        ov.x = Oacc[j4 * 4 + 0] * inv;
        ov.y = Oacc[j4 * 4 + 1] * inv;
        ov.z = Oacc[j4 * 4 + 2] * inv;
        ov.w = Oacc[j4 * 4 + 3] * inv;
        *reinterpret_cast<float4*>(&O[obase + j4 * 4]) = ov;
    }
}

// ---------------------------------------------------------------------------
extern "C" void kernel_launch(void* const* d_in, const int* in_sizes, int n_in,
                              void* d_out, int out_size, void* d_ws, size_t ws_size,
                              hipStream_t stream) {
    const float* query = (const float*)d_in[0];
    const float* key   = (const float*)d_in[1];
    const float* value = (const float*)d_in[2];
    const int*   amask = (const int*)d_in[3];
    const float* wq = (const float*)d_in[4];
    const float* bq = (const float*)d_in[5];
    const float* wk = (const float*)d_in[6];
    const float* bk = (const float*)d_in[7];
    const float* wv = (const float*)d_in[8];
    const float* bv = (const float*)d_in[9];
    const float* wo = (const float*)d_in[10];
    const float* bo = (const float*)d_in[11];
    float* out = (float*)d_out;

    // Per-batch scratch: 4 buffers x H*S*64 floats (8 MB) = 32 MB total,
    // reused across the 4 batches (stream-ordered).
    const size_t PB = (size_t)Hv * Sv * HD;  // 2,097,152 floats
    float* ws = (float*)d_ws;
    float* qb = ws;            // [H,S,64]
    float* kb = qb + PB;       // [H,S,64]
    float* vb = kb + PB;       // [H,S,64]
    float* ab = vb + PB;       // [S,H*64]

    const int M = Sv, N = Hv * HD, K = Dv;
    dim3 gg(N / 64, M / 64);   // (16, 32)
    dim3 bb(256);

    for (int b = 0; b < Bv; ++b) {
        const size_t xoff = (size_t)b * Sv * Dv;
        gemm_k<1><<<gg, bb, 0, stream>>>(query + xoff, wq, bq, qb, M, N, K);
        gemm_k<1><<<gg, bb, 0, stream>>>(key + xoff,   wk, bk, kb, M, N, K);
        gemm_k<1><<<gg, bb, 0, stream>>>(value + xoff, wv, bv, vb, M, N, K);

        attn_k<<<dim3(Sv / 64, Hv), 256, 0, stream>>>(qb, kb, vb,
                                                      amask + (size_t)b * Sv, ab);

        gemm_k<0><<<gg, bb, 0, stream>>>(ab, wo, bo, out + xoff, M, 1024, N);
    }
}

// Round 3
// 832.024 us; speedup vs baseline: 3.2456x; 3.2456x over previous
//
#include <hip/hip_runtime.h>
#include <hip/hip_bf16.h>
#include <math.h>

#define Bv 4
#define Sv 2048
#define Dv 1024
#define Hv 16
#define HD 64
#define NEGV (-1.0e9f)

typedef __attribute__((ext_vector_type(8))) short bf16x8;   // 8 bf16 = 4 VGPRs
typedef __attribute__((ext_vector_type(4))) short s16x4;    // 4 bf16 = 8 B
typedef __attribute__((ext_vector_type(4))) float f32x4;    // MFMA C/D

__device__ __forceinline__ short f2bf(float f) {
    union { __hip_bfloat16 h; short s; } u;
    u.h = __float2bfloat16(f);
    return u.s;
}

// ---------------------------------------------------------------------------
// bf16 MFMA GEMM: C = X[MxK] @ W[KxN] + bias[N].
// 128x128 tile, BK=32, 256 threads = 4 waves (2x2), 4x4 16x16 tiles per wave.
// XBF16: X is bf16 (ushort) else fp32 (converted during staging).
// PERM=1: C bf16 -> [B,H,S,64] layout. PERM=0: C fp32 row-major [M,N].
// LDS strides 40 (80 B rows): frag-read bank stride 20 -> 2-way = free.
// ---------------------------------------------------------------------------
template <int PERM, bool XBF16>
__global__ __launch_bounds__(256) void gemm_mfma(const void* __restrict__ Xv,
                                                 const float* __restrict__ W,
                                                 const float* __restrict__ bias,
                                                 void* __restrict__ Cv,
                                                 int M, int N, int K) {
    __shared__ __align__(16) short As[128][40];  // [m][k]
    __shared__ __align__(16) short Bs[128][40];  // [n][k] (transposed)

    const int t = threadIdx.x;
    const int lane = t & 63, w = t >> 6;
    const int l15 = lane & 15, quad = lane >> 4;
    const int m0 = blockIdx.y * 128, n0 = blockIdx.x * 128;
    const int wm = (w >> 1) * 64, wn = (w & 1) * 64;

    f32x4 acc[4][4];
    #pragma unroll
    for (int mi = 0; mi < 4; ++mi)
        #pragma unroll
        for (int ni = 0; ni < 4; ++ni) acc[mi][ni] = (f32x4){0.f, 0.f, 0.f, 0.f};

    for (int k0 = 0; k0 < K; k0 += 32) {
        // Stage A tile (128x32)
        #pragma unroll
        for (int i = 0; i < 4; ++i) {
            const int c = t + 256 * i;
            const int row = c >> 3, kc = (c & 7) * 4;
            if constexpr (XBF16) {
                const unsigned short* X = (const unsigned short*)Xv;
                s16x4 v = *(const s16x4*)&X[(size_t)(m0 + row) * K + k0 + kc];
                *(s16x4*)&As[row][kc] = v;
            } else {
                const float* X = (const float*)Xv;
                const float4 v =
                    *(const float4*)&X[(size_t)(m0 + row) * K + k0 + kc];
                s16x4 bvec = {f2bf(v.x), f2bf(v.y), f2bf(v.z), f2bf(v.w)};
                *(s16x4*)&As[row][kc] = bvec;
            }
        }
        // Stage B tile (32x128) transposed -> Bs[n][k]
        #pragma unroll
        for (int i = 0; i < 4; ++i) {
            const int c = t + 256 * i;
            const int k = c >> 5, nc = (c & 31) * 4;
            const float4 v = *(const float4*)&W[(size_t)(k0 + k) * N + n0 + nc];
            Bs[nc + 0][k] = f2bf(v.x);
            Bs[nc + 1][k] = f2bf(v.y);
            Bs[nc + 2][k] = f2bf(v.z);
            Bs[nc + 3][k] = f2bf(v.w);
        }
        __syncthreads();

        bf16x8 afr[4], bfr[4];
        #pragma unroll
        for (int mi = 0; mi < 4; ++mi)
            afr[mi] = *(const bf16x8*)&As[wm + mi * 16 + l15][quad * 8];
        #pragma unroll
        for (int ni = 0; ni < 4; ++ni)
            bfr[ni] = *(const bf16x8*)&Bs[wn + ni * 16 + l15][quad * 8];
        #pragma unroll
        for (int mi = 0; mi < 4; ++mi)
            #pragma unroll
            for (int ni = 0; ni < 4; ++ni)
                acc[mi][ni] = __builtin_amdgcn_mfma_f32_16x16x32_bf16(
                    afr[mi], bfr[ni], acc[mi][ni], 0, 0, 0);
        __syncthreads();
    }

    // Epilogue. C/D layout: col = l15, row = quad*4 + r (verified m89/m91).
    #pragma unroll
    for (int mi = 0; mi < 4; ++mi) {
        #pragma unroll
        for (int ni = 0; ni < 4; ++ni) {
            const int col = n0 + wn + ni * 16 + l15;
            const float bsv = bias[col];
            #pragma unroll
            for (int r = 0; r < 4; ++r) {
                const int row = m0 + wm + mi * 16 + quad * 4 + r;
                const float vv = acc[mi][ni][r] + bsv;
                if constexpr (PERM == 0) {
                    ((float*)Cv)[(size_t)row * N + col] = vv;
                } else {
                    const int bb = row / Sv, s = row % Sv;
                    const int hh = col >> 6, d = col & 63;
                    ((unsigned short*)Cv)[((((size_t)bb * Hv + hh) * Sv + s) << 6) + d] =
                        (unsigned short)f2bf(vv);
                }
            }
        }
    }
}

// ---------------------------------------------------------------------------
// bf16 MFMA flash attention. Grid (S/64, H, B), 256 threads = 4 waves.
// Wave w owns q-rows [w*16, w*16+16) of the 64-row tile. Q frags in regs.
// K/V/P tiles in LDS stride 72 (144 B rows): frag bank stride 4 -> 2-way free.
// P goes C-layout -> LDS -> A-layout (the m120-verified transform).
// LDS = 3*64*72*2 + 256 = 27.9 KB -> 5 blocks/CU.
// ---------------------------------------------------------------------------
__global__ __launch_bounds__(256) void attn_mfma(const unsigned short* __restrict__ Q,
                                                 const unsigned short* __restrict__ Kg,
                                                 const unsigned short* __restrict__ V,
                                                 const int* __restrict__ mask,
                                                 unsigned short* __restrict__ O) {
    __shared__ __align__(16) short Kl[64][72];  // [kk][d]
    __shared__ __align__(16) short Vl[64][72];  // [dv][kk] (transposed)
    __shared__ __align__(16) short Sl[64][72];  // [qrow][kk] (P, bf16)
    __shared__ float Mk[64];

    const int t = threadIdx.x;
    const int lane = t & 63, w = t >> 6;
    const int l15 = lane & 15, quad = lane >> 4;
    const int q0 = blockIdx.x * 64;
    const int h = blockIdx.y, b = blockIdx.z;

    const size_t kvbase = ((size_t)b * Hv + h) * Sv * 64;

    // Q A-fragments for this wave's 16 rows; K dim = 64 -> 2 frags. Held all kernel.
    bf16x8 qf[2];
    {
        const size_t qa = kvbase + (size_t)(q0 + w * 16 + l15) * 64 + quad * 8;
        qf[0] = *(const bf16x8*)&Q[qa];
        qf[1] = *(const bf16x8*)&Q[qa + 32];
    }

    float m_i[4], l_i[4];
    f32x4 oacc[4];
    #pragma unroll
    for (int r = 0; r < 4; ++r) { m_i[r] = -INFINITY; l_i[r] = 0.f; }
    #pragma unroll
    for (int ni = 0; ni < 4; ++ni) oacc[ni] = (f32x4){0.f, 0.f, 0.f, 0.f};

    for (int k0 = 0; k0 < Sv; k0 += 64) {
        __syncthreads();  // all waves done reading Kl/Vl from prev iter
        const unsigned short* Ks = Kg + kvbase + (size_t)k0 * 64;
        const unsigned short* Vs = V + kvbase + (size_t)k0 * 64;
        #pragma unroll
        for (int i = 0; i < 4; ++i) {
            const int c = t + 256 * i;
            const int kk = c >> 4, dc = (c & 15) * 4;
            s16x4 kv = *(const s16x4*)&Ks[(size_t)kk * 64 + dc];
            *(s16x4*)&Kl[kk][dc] = kv;
            s16x4 vv = *(const s16x4*)&Vs[(size_t)kk * 64 + dc];
            Vl[dc + 0][kk] = vv[0];
            Vl[dc + 1][kk] = vv[1];
            Vl[dc + 2][kk] = vv[2];
            Vl[dc + 3][kk] = vv[3];
        }
        if (t < 64) Mk[t] = NEGV * (float)mask[(size_t)b * Sv + k0 + t];
        __syncthreads();

        // S = Q K^T : A = Q (m=qrow), B = K (n=kk, k=d)
        f32x4 sacc[4];
        #pragma unroll
        for (int ni = 0; ni < 4; ++ni) {
            sacc[ni] = (f32x4){0.f, 0.f, 0.f, 0.f};
            bf16x8 kf0 = *(const bf16x8*)&Kl[ni * 16 + l15][quad * 8];
            bf16x8 kf1 = *(const bf16x8*)&Kl[ni * 16 + l15][32 + quad * 8];
            sacc[ni] = __builtin_amdgcn_mfma_f32_16x16x32_bf16(qf[0], kf0, sacc[ni], 0, 0, 0);
            sacc[ni] = __builtin_amdgcn_mfma_f32_16x16x32_bf16(qf[1], kf1, sacc[ni], 0, 0, 0);
        }

        // scale + additive mask (col = ni*16 + l15)
        float sc[4][4];
        #pragma unroll
        for (int ni = 0; ni < 4; ++ni) {
            const float mk = Mk[ni * 16 + l15];
            #pragma unroll
            for (int r = 0; r < 4; ++r) sc[ni][r] = sacc[ni][r] * 0.125f + mk;
        }

        // online softmax; row = w*16 + quad*4 + r; reduce across 16 lanes of quad
        #pragma unroll
        for (int r = 0; r < 4; ++r) {
            float mx = fmaxf(fmaxf(sc[0][r], sc[1][r]), fmaxf(sc[2][r], sc[3][r]));
            mx = fmaxf(mx, __shfl_xor(mx, 1, 16));
            mx = fmaxf(mx, __shfl_xor(mx, 2, 16));
            mx = fmaxf(mx, __shfl_xor(mx, 4, 16));
            mx = fmaxf(mx, __shfl_xor(mx, 8, 16));
            const float mnew = fmaxf(m_i[r], mx);
            const float alpha = __expf(m_i[r] - mnew);
            m_i[r] = mnew;
            float rs = 0.f;
            #pragma unroll
            for (int ni = 0; ni < 4; ++ni) {
                const float p = __expf(sc[ni][r] - mnew);
                Sl[w * 16 + quad * 4 + r][ni * 16 + l15] = f2bf(p);
                rs += p;
            }
            rs += __shfl_xor(rs, 1, 16);
            rs += __shfl_xor(rs, 2, 16);
            rs += __shfl_xor(rs, 4, 16);
            rs += __shfl_xor(rs, 8, 16);
            l_i[r] = l_i[r] * alpha + rs;
            #pragma unroll
            for (int ni = 0; ni < 4; ++ni) oacc[ni][r] *= alpha;
        }

        // O += P V : A = P (m=qrow, k=kk) read from own wave's Sl rows;
        //            B = V^T (n=dv, k=kk) from Vl.
        bf16x8 pf0 = *(const bf16x8*)&Sl[w * 16 + l15][quad * 8];
        bf16x8 pf1 = *(const bf16x8*)&Sl[w * 16 + l15][32 + quad * 8];
        #pragma unroll
        for (int ni = 0; ni < 4; ++ni) {
            bf16x8 vf0 = *(const bf16x8*)&Vl[ni * 16 + l15][quad * 8];
            bf16x8 vf1 = *(const bf16x8*)&Vl[ni * 16 + l15][32 + quad * 8];
            oacc[ni] = __builtin_amdgcn_mfma_f32_16x16x32_bf16(pf0, vf0, oacc[ni], 0, 0, 0);
            oacc[ni] = __builtin_amdgcn_mfma_f32_16x16x32_bf16(pf1, vf1, oacc[ni], 0, 0, 0);
        }
    }

    // Write O: [B*S, H*64] bf16
    #pragma unroll
    for (int r = 0; r < 4; ++r) {
        const float inv = 1.0f / l_i[r];
        const size_t row = (size_t)b * Sv + q0 + w * 16 + quad * 4 + r;
        #pragma unroll
        for (int ni = 0; ni < 4; ++ni) {
            O[row * (Hv * HD) + h * HD + ni * 16 + l15] =
                (unsigned short)f2bf(oacc[ni][r] * inv);
        }
    }
}

// ---------------------------------------------------------------------------
extern "C" void kernel_launch(void* const* d_in, const int* in_sizes, int n_in,
                              void* d_out, int out_size, void* d_ws, size_t ws_size,
                              hipStream_t stream) {
    const float* query = (const float*)d_in[0];
    const float* key   = (const float*)d_in[1];
    const float* value = (const float*)d_in[2];
    const int*   amask = (const int*)d_in[3];
    const float* wq = (const float*)d_in[4];
    const float* bq = (const float*)d_in[5];
    const float* wk = (const float*)d_in[6];
    const float* bk = (const float*)d_in[7];
    const float* wv = (const float*)d_in[8];
    const float* bv = (const float*)d_in[9];
    const float* wo = (const float*)d_in[10];
    const float* bo = (const float*)d_in[11];
    float* out = (float*)d_out;

    unsigned short* ws = (unsigned short*)d_ws;

    if (ws_size >= (size_t)64 * 1024 * 1024) {
        // All-batch path: q/k/v bf16 [B,H,S,64] (16 MB each) + ab bf16 (16 MB).
        const size_t PBQ = (size_t)Bv * Hv * Sv * HD;
        unsigned short* qb = ws;
        unsigned short* kb = qb + PBQ;
        unsigned short* vb = kb + PBQ;
        unsigned short* ab = vb + PBQ;
        dim3 gg(1024 / 128, (Bv * Sv) / 128);  // (8, 64) = 512 blocks
        gemm_mfma<1, false><<<gg, 256, 0, stream>>>(query, wq, bq, qb, Bv * Sv, 1024, 1024);
        gemm_mfma<1, false><<<gg, 256, 0, stream>>>(key,   wk, bk, kb, Bv * Sv, 1024, 1024);
        gemm_mfma<1, false><<<gg, 256, 0, stream>>>(value, wv, bv, vb, Bv * Sv, 1024, 1024);
        attn_mfma<<<dim3(Sv / 64, Hv, Bv), 256, 0, stream>>>(qb, kb, vb, amask, ab);
        gemm_mfma<0, true><<<gg, 256, 0, stream>>>(ab, wo, bo, out, Bv * Sv, 1024, 1024);
    } else {
        // Per-batch fallback (16 MB scratch).
        const size_t PQ = (size_t)Hv * Sv * HD;
        unsigned short* qb = ws;
        unsigned short* kb = qb + PQ;
        unsigned short* vb = kb + PQ;
        unsigned short* ab = vb + PQ;
        dim3 gg(1024 / 128, Sv / 128);  // (8, 16)
        for (int b = 0; b < Bv; ++b) {
            const size_t xoff = (size_t)b * Sv * Dv;
            gemm_mfma<1, false><<<gg, 256, 0, stream>>>(query + xoff, wq, bq, qb, Sv, 1024, 1024);
            gemm_mfma<1, false><<<gg, 256, 0, stream>>>(key + xoff,   wk, bk, kb, Sv, 1024, 1024);
            gemm_mfma<1, false><<<gg, 256, 0, stream>>>(value + xoff, wv, bv, vb, Sv, 1024, 1024);
            attn_mfma<<<dim3(Sv / 64, Hv, 1), 256, 0, stream>>>(qb, kb, vb,
                                                                amask + (size_t)b * Sv, ab);
            gemm_mfma<0, true><<<gg, 256, 0, stream>>>(ab, wo, bo, out + xoff, Sv, 1024, 1024);
        }
    }
}

// Round 4
// 456.366 us; speedup vs baseline: 5.9172x; 1.8232x over previous
//
#include <hip/hip_runtime.h>
#include <hip/hip_bf16.h>
#include <math.h>

#define Bv 4
#define Sv 2048
#define Dv 1024
#define Hv 16
#define HD 64
#define NEGV (-1.0e9f)

typedef __attribute__((ext_vector_type(8))) short bf16x8;   // 8 bf16 = 16 B
typedef __attribute__((ext_vector_type(4))) short s16x4;    // 4 bf16 = 8 B
typedef __attribute__((ext_vector_type(4))) float f32x4;    // MFMA C/D

__device__ __forceinline__ short f2bf(float f) {
    union { __hip_bfloat16 h; short s; } u;
    u.h = __float2bfloat16(f);
    return u.s;
}

__device__ __forceinline__ void glds16(const void* g, void* l) {
    __builtin_amdgcn_global_load_lds(
        (const __attribute__((address_space(1))) void*)g,
        (__attribute__((address_space(3))) void*)l, 16, 0, 0);
}

// ---------------------------------------------------------------------------
// fp32 W [K=1024][N=1024] -> bf16 W^T [N][K]. Grid (16,16), 256 thr.
// ---------------------------------------------------------------------------
__global__ __launch_bounds__(256) void transpose_w(const float* __restrict__ W,
                                                   unsigned short* __restrict__ WT) {
    __shared__ float T[64][65];
    const int t = threadIdx.x;
    const int n0 = blockIdx.x * 64, k0 = blockIdx.y * 64;
    #pragma unroll
    for (int i = 0; i < 4; ++i) {
        const int k = (t >> 4) + 16 * i;
        const int nc = (t & 15) * 4;
        const float4 v = *(const float4*)&W[(size_t)(k0 + k) * 1024 + n0 + nc];
        T[k][nc + 0] = v.x; T[k][nc + 1] = v.y;
        T[k][nc + 2] = v.z; T[k][nc + 3] = v.w;
    }
    __syncthreads();
    const int n = t >> 2, kc = (t & 3) * 16;
    #pragma unroll
    for (int j4 = 0; j4 < 4; ++j4) {
        s16x4 o;
        #pragma unroll
        for (int jj = 0; jj < 4; ++jj) o[jj] = f2bf(T[kc + j4 * 4 + jj][n]);
        *(s16x4*)&WT[(size_t)(n0 + n) * 1024 + k0 + kc + j4 * 4] = o;
    }
}

// ---------------------------------------------------------------------------
// bf16 V [BH][S][64] -> V^T [BH][64][S]. Grid (S/64, B*H), 256 thr.
// ---------------------------------------------------------------------------
__global__ __launch_bounds__(256) void transpose_v(const unsigned short* __restrict__ Vin,
                                                   unsigned short* __restrict__ VT) {
    __shared__ unsigned short T[64][72];
    const int t = threadIdx.x;
    const int s0 = blockIdx.x * 64;
    const int bh = blockIdx.y;
    const size_t ib = (size_t)bh * Sv * 64;
    const size_t ob = (size_t)bh * 64 * Sv;
    {
        const int s = t >> 2, dc = (t & 3) * 16;
        const bf16x8 a = *(const bf16x8*)&Vin[ib + (size_t)(s0 + s) * 64 + dc];
        const bf16x8 b = *(const bf16x8*)&Vin[ib + (size_t)(s0 + s) * 64 + dc + 8];
        *(bf16x8*)&T[s][dc] = a;
        *(bf16x8*)&T[s][dc + 8] = b;
    }
    __syncthreads();
    const int dv = t >> 2, sc = (t & 3) * 16;
    #pragma unroll
    for (int j4 = 0; j4 < 4; ++j4) {
        s16x4 o;
        #pragma unroll
        for (int jj = 0; jj < 4; ++jj) o[jj] = (short)T[sc + j4 * 4 + jj][dv];
        *(s16x4*)&VT[ob + (size_t)dv * Sv + s0 + sc + j4 * 4] = o;
    }
}

// ---------------------------------------------------------------------------
// bf16 MFMA GEMM: C = X[MxK] @ W + bias, weights given as bf16 W^T [N][K].
// 128x128 tile, BK=32, 256 thr = 4 waves (2x2), 4x4 16x16x32 MFMA per wave.
// B staged via global_load_lds (conflict-free, no VALU). A: fp32->bf16 cvt
// path (stride 40) or, if XBF16, global_load_lds (stride 32).
// PERM=1: C bf16 -> [B,H,S,64]. PERM=0: C fp32 row-major [M,N].
// ---------------------------------------------------------------------------
template <int PERM, bool XBF16>
__global__ __launch_bounds__(256) void gemm_mfma(const void* __restrict__ Xv,
                                                 const unsigned short* __restrict__ WT,
                                                 const float* __restrict__ bias,
                                                 void* __restrict__ Cv,
                                                 int M, int N, int K) {
    constexpr int AST = XBF16 ? 32 : 40;
    __shared__ short As[128 * AST];
    __shared__ short Bs[128 * 32];

    const int t = threadIdx.x;
    const int lane = t & 63, w = t >> 6;
    const int l15 = lane & 15, quad = lane >> 4;
    const int m0 = blockIdx.y * 128, n0 = blockIdx.x * 128;
    const int wm = (w >> 1) * 64, wn = (w & 1) * 64;

    f32x4 acc[4][4];
    #pragma unroll
    for (int mi = 0; mi < 4; ++mi)
        #pragma unroll
        for (int ni = 0; ni < 4; ++ni) acc[mi][ni] = (f32x4){0.f, 0.f, 0.f, 0.f};

    for (int k0 = 0; k0 < K; k0 += 32) {
        // B tile: 128 rows(n) x 32 k, via global_load_lds (8 segs of 16 rows)
        #pragma unroll
        for (int i = 0; i < 2; ++i) {
            const int seg = w * 2 + i;
            const int row = seg * 16 + (lane >> 2);
            const int kc = (lane & 3) * 8;
            glds16(&WT[(size_t)(n0 + row) * K + k0 + kc], &Bs[seg * 512]);
        }
        // A tile
        if constexpr (XBF16) {
            const unsigned short* X = (const unsigned short*)Xv;
            #pragma unroll
            for (int i = 0; i < 2; ++i) {
                const int seg = w * 2 + i;
                const int row = seg * 16 + (lane >> 2);
                const int kc = (lane & 3) * 8;
                glds16(&X[(size_t)(m0 + row) * K + k0 + kc], &As[seg * 512]);
            }
        } else {
            const float* X = (const float*)Xv;
            #pragma unroll
            for (int i = 0; i < 4; ++i) {
                const int c = t + 256 * i;
                const int row = c >> 3, kc = (c & 7) * 4;
                const float4 v = *(const float4*)&X[(size_t)(m0 + row) * K + k0 + kc];
                s16x4 bvec = {f2bf(v.x), f2bf(v.y), f2bf(v.z), f2bf(v.w)};
                *(s16x4*)&As[row * AST + kc] = bvec;
            }
        }
        __syncthreads();

        bf16x8 afr[4], bfr[4];
        #pragma unroll
        for (int mi = 0; mi < 4; ++mi)
            afr[mi] = *(const bf16x8*)&As[(wm + mi * 16 + l15) * AST + quad * 8];
        #pragma unroll
        for (int ni = 0; ni < 4; ++ni)
            bfr[ni] = *(const bf16x8*)&Bs[(wn + ni * 16 + l15) * 32 + quad * 8];
        #pragma unroll
        for (int mi = 0; mi < 4; ++mi)
            #pragma unroll
            for (int ni = 0; ni < 4; ++ni)
                acc[mi][ni] = __builtin_amdgcn_mfma_f32_16x16x32_bf16(
                    afr[mi], bfr[ni], acc[mi][ni], 0, 0, 0);
        __syncthreads();
    }

    // Epilogue. C/D: col = l15, row = quad*4 + r.
    #pragma unroll
    for (int mi = 0; mi < 4; ++mi) {
        #pragma unroll
        for (int ni = 0; ni < 4; ++ni) {
            const int col = n0 + wn + ni * 16 + l15;
            const float bsv = bias[col];
            #pragma unroll
            for (int r = 0; r < 4; ++r) {
                const int row = m0 + wm + mi * 16 + quad * 4 + r;
                const float vv = acc[mi][ni][r] + bsv;
                if constexpr (PERM == 0) {
                    ((float*)Cv)[(size_t)row * N + col] = vv;
                } else {
                    const int bb = row / Sv, s = row % Sv;
                    const int hh = col >> 6, d = col & 63;
                    ((unsigned short*)Cv)[((((size_t)bb * Hv + hh) * Sv + s) << 6) + d] =
                        (unsigned short)f2bf(vv);
                }
            }
        }
    }
}

// ---------------------------------------------------------------------------
// Flash attention, S^T form, no-max softmax. Grid (S/64, H, B), 256 thr.
// Q,K in [BH][S][64]; V^T in [BH][64][S]; out [B*S][H*64] bf16.
// Wave w owns q-rows [w*16, w*16+16). S^T = K·Q^T so each lane owns one
// q-row (l15) -> P transposes to A-layout with 4 vector b64 writes.
// l_i: one register per lane, reduced once at the end.
// ---------------------------------------------------------------------------
__global__ __launch_bounds__(256) void attn_mfma(const unsigned short* __restrict__ Q,
                                                 const unsigned short* __restrict__ Kg,
                                                 const unsigned short* __restrict__ VT,
                                                 const int* __restrict__ mask,
                                                 unsigned short* __restrict__ O) {
    __shared__ short Kl[64 * 72];   // [kk][d]
    __shared__ short Vl[64 * 72];   // [dv][kk]
    __shared__ short Sl[64 * 72];   // [qrow][kk]
    __shared__ float Mk[64];

    const int t = threadIdx.x;
    const int lane = t & 63, w = t >> 6;
    const int l15 = lane & 15, quad = lane >> 4;
    const int q0 = blockIdx.x * 64;
    const int h = blockIdx.y, b = blockIdx.z;
    const int bh = b * Hv + h;
    const size_t kvb = (size_t)bh * Sv * 64;
    const size_t vtb = (size_t)bh * 64 * Sv;

    // Q B-fragments (n = qrow = l15): held in regs all kernel.
    bf16x8 qf[2];
    {
        const size_t qa = kvb + (size_t)(q0 + w * 16 + l15) * 64 + quad * 8;
        qf[0] = *(const bf16x8*)&Q[qa];
        qf[1] = *(const bf16x8*)&Q[qa + 32];
    }

    float l_acc = 0.0f;
    f32x4 oacc[4];
    #pragma unroll
    for (int ni = 0; ni < 4; ++ni) oacc[ni] = (f32x4){0.f, 0.f, 0.f, 0.f};

    const int srow = t >> 2, sch = (t & 3) * 16;   // staging map: 16 shorts/thr

    for (int k0 = 0; k0 < Sv; k0 += 64) {
        __syncthreads();
        // Stage K tile [kk][d] and V^T tile [dv][kk]
        {
            const unsigned short* Ks = Kg + kvb + (size_t)k0 * 64;
            const bf16x8 a = *(const bf16x8*)&Ks[(size_t)srow * 64 + sch];
            const bf16x8 c = *(const bf16x8*)&Ks[(size_t)srow * 64 + sch + 8];
            *(bf16x8*)&Kl[srow * 72 + sch] = a;
            *(bf16x8*)&Kl[srow * 72 + sch + 8] = c;
            const unsigned short* Vs = VT + vtb + k0;
            const bf16x8 d = *(const bf16x8*)&Vs[(size_t)srow * Sv + sch];
            const bf16x8 e = *(const bf16x8*)&Vs[(size_t)srow * Sv + sch + 8];
            *(bf16x8*)&Vl[srow * 72 + sch] = d;
            *(bf16x8*)&Vl[srow * 72 + sch + 8] = e;
        }
        if (t < 64) Mk[t] = NEGV * (float)mask[(size_t)b * Sv + k0 + t];
        __syncthreads();

        // S^T = K·Q^T : A = K frags (m = kk), B = Q frags (n = qrow).
        #pragma unroll
        for (int mi = 0; mi < 4; ++mi) {
            const bf16x8 kf0 = *(const bf16x8*)&Kl[(mi * 16 + l15) * 72 + quad * 8];
            const bf16x8 kf1 = *(const bf16x8*)&Kl[(mi * 16 + l15) * 72 + 32 + quad * 8];
            f32x4 st = (f32x4){0.f, 0.f, 0.f, 0.f};
            st = __builtin_amdgcn_mfma_f32_16x16x32_bf16(kf0, qf[0], st, 0, 0, 0);
            st = __builtin_amdgcn_mfma_f32_16x16x32_bf16(kf1, qf[1], st, 0, 0, 0);
            // rows kk = mi*16 + quad*4 + r ; col qrow = l15
            const float4 mk4 = *(const float4*)&Mk[mi * 16 + quad * 4];
            float p0 = __expf(st[0] * 0.125f + mk4.x);
            float p1 = __expf(st[1] * 0.125f + mk4.y);
            float p2 = __expf(st[2] * 0.125f + mk4.z);
            float p3 = __expf(st[3] * 0.125f + mk4.w);
            l_acc += (p0 + p1) + (p2 + p3);
            s16x4 pv = {f2bf(p0), f2bf(p1), f2bf(p2), f2bf(p3)};
            *(s16x4*)&Sl[(w * 16 + l15) * 72 + mi * 16 + quad * 4] = pv;
        }

        // O += P·V : A = P frags (own wave rows), B = V^T frags.
        const bf16x8 pf0 = *(const bf16x8*)&Sl[(w * 16 + l15) * 72 + quad * 8];
        const bf16x8 pf1 = *(const bf16x8*)&Sl[(w * 16 + l15) * 72 + 32 + quad * 8];
        #pragma unroll
        for (int ni = 0; ni < 4; ++ni) {
            const bf16x8 vf0 = *(const bf16x8*)&Vl[(ni * 16 + l15) * 72 + quad * 8];
            const bf16x8 vf1 = *(const bf16x8*)&Vl[(ni * 16 + l15) * 72 + 32 + quad * 8];
            oacc[ni] = __builtin_amdgcn_mfma_f32_16x16x32_bf16(pf0, vf0, oacc[ni], 0, 0, 0);
            oacc[ni] = __builtin_amdgcn_mfma_f32_16x16x32_bf16(pf1, vf1, oacc[ni], 0, 0, 0);
        }
    }

    // Row sums: reduce across quads, then fetch l for this lane's output rows.
    l_acc += __shfl_xor(l_acc, 16);
    l_acc += __shfl_xor(l_acc, 32);
    #pragma unroll
    for (int r = 0; r < 4; ++r) {
        const float lr = __shfl(l_acc, quad * 4 + r, 64);
        const float inv = 1.0f / lr;
        const size_t row = (size_t)b * Sv + q0 + w * 16 + quad * 4 + r;
        #pragma unroll
        for (int ni = 0; ni < 4; ++ni) {
            O[row * (Hv * HD) + h * HD + ni * 16 + l15] =
                (unsigned short)f2bf(oacc[ni][r] * inv);
        }
    }
}

// ---------------------------------------------------------------------------
extern "C" void kernel_launch(void* const* d_in, const int* in_sizes, int n_in,
                              void* d_out, int out_size, void* d_ws, size_t ws_size,
                              hipStream_t stream) {
    const float* query = (const float*)d_in[0];
    const float* key   = (const float*)d_in[1];
    const float* value = (const float*)d_in[2];
    const int*   amask = (const int*)d_in[3];
    const float* wq = (const float*)d_in[4];
    const float* bq = (const float*)d_in[5];
    const float* wk = (const float*)d_in[6];
    const float* bk = (const float*)d_in[7];
    const float* wv = (const float*)d_in[8];
    const float* bv = (const float*)d_in[9];
    const float* wo = (const float*)d_in[10];
    const float* bo = (const float*)d_in[11];
    float* out = (float*)d_out;

    // ws (64 MB): qb | kb | vb | ab, 16 MB each (bf16, 8M elems).
    // wt (2 MB bf16 W^T) aliases the head of ab (dead until attn) and later vb.
    const size_t PBQ = (size_t)Bv * Hv * Sv * HD;  // 8,388,608
    unsigned short* wsp = (unsigned short*)d_ws;
    unsigned short* qb = wsp;
    unsigned short* kb = qb + PBQ;
    unsigned short* vb = kb + PBQ;
    unsigned short* ab = vb + PBQ;
    unsigned short* wt_ab = ab;   // W^T scratch while ab unused
    unsigned short* wt_vb = vb;   // W^T scratch after attn (vb dead)

    const int M = Bv * Sv;                     // 8192
    dim3 gt(16, 16), gg(8, M / 128), bb(256);

    // 1) V path first: T(wv) -> ab-head ; V-GEMM -> kb (temp) ; Tv: kb -> vb
    transpose_w<<<gt, bb, 0, stream>>>(wv, wt_ab);
    gemm_mfma<1, false><<<gg, bb, 0, stream>>>(value, wt_ab, bv, kb, M, 1024, 1024);
    transpose_v<<<dim3(Sv / 64, Bv * Hv), bb, 0, stream>>>(kb, vb);

    // 2) Q and K projections (kb temp is dead, overwritten by K)
    transpose_w<<<gt, bb, 0, stream>>>(wq, wt_ab);
    gemm_mfma<1, false><<<gg, bb, 0, stream>>>(query, wt_ab, bq, qb, M, 1024, 1024);
    transpose_w<<<gt, bb, 0, stream>>>(wk, wt_ab);
    gemm_mfma<1, false><<<gg, bb, 0, stream>>>(key, wt_ab, bk, kb, M, 1024, 1024);

    // 3) Attention -> ab (overwrites wt_ab; it is dead now)
    attn_mfma<<<dim3(Sv / 64, Hv, Bv), bb, 0, stream>>>(qb, kb, vb, amask, ab);

    // 4) Output projection: T(wo) -> vb-head (vb dead) ; out = ab @ wo + bo
    transpose_w<<<gt, bb, 0, stream>>>(wo, wt_vb);
    gemm_mfma<0, true><<<gg, bb, 0, stream>>>(ab, wt_vb, bo, out, M, 1024, 1024);
}

// Round 5
// 409.347 us; speedup vs baseline: 6.5969x; 1.1149x over previous
//
#include <hip/hip_runtime.h>
#include <hip/hip_bf16.h>
#include <math.h>

#define Bv 4
#define Sv 2048
#define Dv 1024
#define Hv 16
#define HD 64
#define NEGV (-1.0e9f)

typedef __attribute__((ext_vector_type(8))) short bf16x8;   // 8 bf16 = 16 B
typedef __attribute__((ext_vector_type(4))) short s16x4;    // 4 bf16 = 8 B
typedef __attribute__((ext_vector_type(4))) float f32x4;    // MFMA C/D

__device__ __forceinline__ short f2bf(float f) {
    union { __hip_bfloat16 h; short s; } u;
    u.h = __float2bfloat16(f);
    return u.s;
}

__device__ __forceinline__ void glds16(const void* g, void* l) {
    __builtin_amdgcn_global_load_lds(
        (const __attribute__((address_space(1))) void*)g,
        (__attribute__((address_space(3))) void*)l, 16, 0, 0);
}

// ---------------------------------------------------------------------------
// fp32 -> bf16 bulk convert. 8 elems/thread. n must be /2048.
// ---------------------------------------------------------------------------
__global__ __launch_bounds__(256) void cvt_bf16(const float* __restrict__ X,
                                                unsigned short* __restrict__ Y) {
    const size_t i = ((size_t)blockIdx.x * 256 + threadIdx.x) * 8;
    const float4 a = *(const float4*)&X[i];
    const float4 b = *(const float4*)&X[i + 4];
    bf16x8 o = {f2bf(a.x), f2bf(a.y), f2bf(a.z), f2bf(a.w),
                f2bf(b.x), f2bf(b.y), f2bf(b.z), f2bf(b.w)};
    *(bf16x8*)&Y[i] = o;
}

// ---------------------------------------------------------------------------
// fp32 W [K=1024][N=1024] -> bf16 W^T [N][K]. Grid (16,16), 256 thr.
// ---------------------------------------------------------------------------
__global__ __launch_bounds__(256) void transpose_w(const float* __restrict__ W,
                                                   unsigned short* __restrict__ WT) {
    __shared__ float T[64][65];
    const int t = threadIdx.x;
    const int n0 = blockIdx.x * 64, k0 = blockIdx.y * 64;
    #pragma unroll
    for (int i = 0; i < 4; ++i) {
        const int k = (t >> 4) + 16 * i;
        const int nc = (t & 15) * 4;
        const float4 v = *(const float4*)&W[(size_t)(k0 + k) * 1024 + n0 + nc];
        T[k][nc + 0] = v.x; T[k][nc + 1] = v.y;
        T[k][nc + 2] = v.z; T[k][nc + 3] = v.w;
    }
    __syncthreads();
    const int n = t >> 2, kc = (t & 3) * 16;
    #pragma unroll
    for (int j4 = 0; j4 < 4; ++j4) {
        s16x4 o;
        #pragma unroll
        for (int jj = 0; jj < 4; ++jj) o[jj] = f2bf(T[kc + j4 * 4 + jj][n]);
        *(s16x4*)&WT[(size_t)(n0 + n) * 1024 + k0 + kc + j4 * 4] = o;
    }
}

// ---------------------------------------------------------------------------
// bf16 V [BH][S][64] -> V^T [BH][64][S]. Grid (S/64, nBH), 256 thr.
// ---------------------------------------------------------------------------
__global__ __launch_bounds__(256) void transpose_v(const unsigned short* __restrict__ Vin,
                                                   unsigned short* __restrict__ VT) {
    __shared__ unsigned short T[64][72];
    const int t = threadIdx.x;
    const int s0 = blockIdx.x * 64;
    const int bh = blockIdx.y;
    const size_t ib = (size_t)bh * Sv * 64;
    const size_t ob = (size_t)bh * 64 * Sv;
    {
        const int s = t >> 2, dc = (t & 3) * 16;
        const bf16x8 a = *(const bf16x8*)&Vin[ib + (size_t)(s0 + s) * 64 + dc];
        const bf16x8 b = *(const bf16x8*)&Vin[ib + (size_t)(s0 + s) * 64 + dc + 8];
        *(bf16x8*)&T[s][dc] = a;
        *(bf16x8*)&T[s][dc + 8] = b;
    }
    __syncthreads();
    const int dv = t >> 2, sc = (t & 3) * 16;
    #pragma unroll
    for (int j4 = 0; j4 < 4; ++j4) {
        s16x4 o;
        #pragma unroll
        for (int jj = 0; jj < 4; ++jj) o[jj] = (short)T[sc + j4 * 4 + jj][dv];
        *(s16x4*)&VT[ob + (size_t)dv * Sv + s0 + sc + j4 * 4] = o;
    }
}

// ---------------------------------------------------------------------------
// bf16 MFMA GEMM: C = X[MxK](bf16) @ W + bias, weights as bf16 W^T [N][K].
// 128x128 tile, BK=32, 256 thr = 4 waves (2x2), 4x4 16x16x32 MFMA per wave.
// Both operands staged via global_load_lds width-16 (m97 structure).
// PERM=1: C bf16 -> [B,H,S,64]. PERM=0: C fp32 row-major [M,N].
// ---------------------------------------------------------------------------
template <int PERM>
__global__ __launch_bounds__(256) void gemm_mfma(const unsigned short* __restrict__ X,
                                                 const unsigned short* __restrict__ WT,
                                                 const float* __restrict__ bias,
                                                 void* __restrict__ Cv,
                                                 int M, int N, int K) {
    __shared__ short As[128 * 32];
    __shared__ short Bs[128 * 32];

    const int t = threadIdx.x;
    const int lane = t & 63, w = t >> 6;
    const int l15 = lane & 15, quad = lane >> 4;
    const int m0 = blockIdx.y * 128, n0 = blockIdx.x * 128;
    const int wm = (w >> 1) * 64, wn = (w & 1) * 64;

    f32x4 acc[4][4];
    #pragma unroll
    for (int mi = 0; mi < 4; ++mi)
        #pragma unroll
        for (int ni = 0; ni < 4; ++ni) acc[mi][ni] = (f32x4){0.f, 0.f, 0.f, 0.f};

    const int srow = lane >> 2;          // 16 rows per seg
    const int skc = (lane & 3) * 8;      // 8 bf16 = 16 B per lane

    for (int k0 = 0; k0 < K; k0 += 32) {
        #pragma unroll
        for (int i = 0; i < 2; ++i) {
            const int seg = w * 2 + i;
            const int row = seg * 16 + srow;
            glds16(&WT[(size_t)(n0 + row) * K + k0 + skc], &Bs[seg * 512]);
            glds16(&X[(size_t)(m0 + row) * K + k0 + skc], &As[seg * 512]);
        }
        __syncthreads();

        bf16x8 afr[4], bfr[4];
        #pragma unroll
        for (int mi = 0; mi < 4; ++mi)
            afr[mi] = *(const bf16x8*)&As[(wm + mi * 16 + l15) * 32 + quad * 8];
        #pragma unroll
        for (int ni = 0; ni < 4; ++ni)
            bfr[ni] = *(const bf16x8*)&Bs[(wn + ni * 16 + l15) * 32 + quad * 8];
        #pragma unroll
        for (int mi = 0; mi < 4; ++mi)
            #pragma unroll
            for (int ni = 0; ni < 4; ++ni)
                acc[mi][ni] = __builtin_amdgcn_mfma_f32_16x16x32_bf16(
                    afr[mi], bfr[ni], acc[mi][ni], 0, 0, 0);
        __syncthreads();
    }

    // Epilogue. C/D: col = l15, row = quad*4 + r.
    #pragma unroll
    for (int mi = 0; mi < 4; ++mi) {
        #pragma unroll
        for (int ni = 0; ni < 4; ++ni) {
            const int col = n0 + wn + ni * 16 + l15;
            const float bsv = bias[col];
            #pragma unroll
            for (int r = 0; r < 4; ++r) {
                const int row = m0 + wm + mi * 16 + quad * 4 + r;
                const float vv = acc[mi][ni][r] + bsv;
                if constexpr (PERM == 0) {
                    ((float*)Cv)[(size_t)row * N + col] = vv;
                } else {
                    const int bb = row / Sv, s = row % Sv;
                    const int hh = col >> 6, d = col & 63;
                    ((unsigned short*)Cv)[((((size_t)bb * Hv + hh) * Sv + s) << 6) + d] =
                        (unsigned short)f2bf(vv);
                }
            }
        }
    }
}

// ---------------------------------------------------------------------------
// Flash attention, S^T form, no-max softmax, 128-q-row tiles.
// Grid (S/128, H, B), 256 thr = 4 waves; wave w owns q-rows [w*32, w*32+32).
// Q,K in [BH][S][64]; V^T in [BH][64][S]; out [B*S][H*64] bf16.
// S^T = K·Q^T -> each lane owns one q-row (col l15): P transposes to
// A-layout with vector b64 writes to wave-private Sl rows (no extra barrier).
// LDS = (64+64+128)*72*2 + 256 = 37.1 KB -> 4 blocks/CU.
// ---------------------------------------------------------------------------
__global__ __launch_bounds__(256) void attn_mfma(const unsigned short* __restrict__ Q,
                                                 const unsigned short* __restrict__ Kg,
                                                 const unsigned short* __restrict__ VT,
                                                 const int* __restrict__ mask,
                                                 unsigned short* __restrict__ O) {
    __shared__ short Kl[64 * 72];    // [kk][d]
    __shared__ short Vl[64 * 72];    // [dv][kk]
    __shared__ short Sl[128 * 72];   // [qrow][kk]
    __shared__ float Mk[64];

    const int t = threadIdx.x;
    const int lane = t & 63, w = t >> 6;
    const int l15 = lane & 15, quad = lane >> 4;
    const int q0 = blockIdx.x * 128;
    const int h = blockIdx.y, b = blockIdx.z;
    const int bh = b * Hv + h;
    const size_t kvb = (size_t)bh * Sv * 64;
    const size_t vtb = (size_t)bh * 64 * Sv;

    // Q B-fragments for 2 q-subtiles (n = qrow): held in regs all kernel.
    bf16x8 qf[2][2];
    #pragma unroll
    for (int ni = 0; ni < 2; ++ni) {
        const size_t qa = kvb + (size_t)(q0 + w * 32 + ni * 16 + l15) * 64 + quad * 8;
        qf[ni][0] = *(const bf16x8*)&Q[qa];
        qf[ni][1] = *(const bf16x8*)&Q[qa + 32];
    }

    float l_acc[2] = {0.f, 0.f};
    f32x4 oacc[2][4];
    #pragma unroll
    for (int mi = 0; mi < 2; ++mi)
        #pragma unroll
        for (int ni = 0; ni < 4; ++ni) oacc[mi][ni] = (f32x4){0.f, 0.f, 0.f, 0.f};

    const int srow = t >> 2, sch = (t & 3) * 16;   // staging: 16 shorts/thread

    for (int k0 = 0; k0 < Sv; k0 += 64) {
        __syncthreads();
        {
            const unsigned short* Ks = Kg + kvb + (size_t)k0 * 64;
            const bf16x8 a = *(const bf16x8*)&Ks[(size_t)srow * 64 + sch];
            const bf16x8 c = *(const bf16x8*)&Ks[(size_t)srow * 64 + sch + 8];
            *(bf16x8*)&Kl[srow * 72 + sch] = a;
            *(bf16x8*)&Kl[srow * 72 + sch + 8] = c;
            const unsigned short* Vs = VT + vtb + k0;
            const bf16x8 d = *(const bf16x8*)&Vs[(size_t)srow * Sv + sch];
            const bf16x8 e = *(const bf16x8*)&Vs[(size_t)srow * Sv + sch + 8];
            *(bf16x8*)&Vl[srow * 72 + sch] = d;
            *(bf16x8*)&Vl[srow * 72 + sch + 8] = e;
        }
        if (t < 64) Mk[t] = NEGV * (float)mask[(size_t)b * Sv + k0 + t];
        __syncthreads();

        // S^T = K·Q^T : A = K (m = kk), B = Q (n = qrow).
        #pragma unroll
        for (int mi = 0; mi < 4; ++mi) {
            const bf16x8 kf0 = *(const bf16x8*)&Kl[(mi * 16 + l15) * 72 + quad * 8];
            const bf16x8 kf1 = *(const bf16x8*)&Kl[(mi * 16 + l15) * 72 + 32 + quad * 8];
            const float4 mk4 = *(const float4*)&Mk[mi * 16 + quad * 4];
            #pragma unroll
            for (int ni = 0; ni < 2; ++ni) {
                f32x4 st = (f32x4){0.f, 0.f, 0.f, 0.f};
                st = __builtin_amdgcn_mfma_f32_16x16x32_bf16(kf0, qf[ni][0], st, 0, 0, 0);
                st = __builtin_amdgcn_mfma_f32_16x16x32_bf16(kf1, qf[ni][1], st, 0, 0, 0);
                const float p0 = __expf(st[0] * 0.125f + mk4.x);
                const float p1 = __expf(st[1] * 0.125f + mk4.y);
                const float p2 = __expf(st[2] * 0.125f + mk4.z);
                const float p3 = __expf(st[3] * 0.125f + mk4.w);
                l_acc[ni] += (p0 + p1) + (p2 + p3);
                s16x4 pv = {f2bf(p0), f2bf(p1), f2bf(p2), f2bf(p3)};
                *(s16x4*)&Sl[(w * 32 + ni * 16 + l15) * 72 + mi * 16 + quad * 4] = pv;
            }
        }

        // O += P·V : A = P (wave-private Sl rows), B = V^T.
        #pragma unroll
        for (int mi = 0; mi < 2; ++mi) {
            const bf16x8 pf0 = *(const bf16x8*)&Sl[(w * 32 + mi * 16 + l15) * 72 + quad * 8];
            const bf16x8 pf1 = *(const bf16x8*)&Sl[(w * 32 + mi * 16 + l15) * 72 + 32 + quad * 8];
            #pragma unroll
            for (int ni = 0; ni < 4; ++ni) {
                const bf16x8 vf0 = *(const bf16x8*)&Vl[(ni * 16 + l15) * 72 + quad * 8];
                const bf16x8 vf1 = *(const bf16x8*)&Vl[(ni * 16 + l15) * 72 + 32 + quad * 8];
                oacc[mi][ni] = __builtin_amdgcn_mfma_f32_16x16x32_bf16(pf0, vf0, oacc[mi][ni], 0, 0, 0);
                oacc[mi][ni] = __builtin_amdgcn_mfma_f32_16x16x32_bf16(pf1, vf1, oacc[mi][ni], 0, 0, 0);
            }
        }
    }

    // Row sums: reduce across quads, fetch l per output row, write O.
    #pragma unroll
    for (int mi = 0; mi < 2; ++mi) {
        float l = l_acc[mi];
        l += __shfl_xor(l, 16);
        l += __shfl_xor(l, 32);
        #pragma unroll
        for (int r = 0; r < 4; ++r) {
            const float lr = __shfl(l, quad * 4 + r, 64);
            const float inv = 1.0f / lr;
            const size_t row = (size_t)b * Sv + q0 + w * 32 + mi * 16 + quad * 4 + r;
            #pragma unroll
            for (int ni = 0; ni < 4; ++ni) {
                O[row * (Hv * HD) + h * HD + ni * 16 + l15] =
                    (unsigned short)f2bf(oacc[mi][ni][r] * inv);
            }
        }
    }
}

// ---------------------------------------------------------------------------
extern "C" void kernel_launch(void* const* d_in, const int* in_sizes, int n_in,
                              void* d_out, int out_size, void* d_ws, size_t ws_size,
                              hipStream_t stream) {
    const float* query = (const float*)d_in[0];
    const float* key   = (const float*)d_in[1];
    const float* value = (const float*)d_in[2];
    const int*   amask = (const int*)d_in[3];
    const float* wq = (const float*)d_in[4];
    const float* bq = (const float*)d_in[5];
    const float* wk = (const float*)d_in[6];
    const float* bk = (const float*)d_in[7];
    const float* wv = (const float*)d_in[8];
    const float* bv = (const float*)d_in[9];
    const float* wo = (const float*)d_in[10];
    const float* bo = (const float*)d_in[11];
    float* out = (float*)d_out;

    unsigned short* wsp = (unsigned short*)d_ws;
    dim3 bb(256), gt(16, 16);

    if (ws_size >= (size_t)64 * 1024 * 1024) {
        // ws: qb | kb | vb | ab (16 MB each, bf16 8M elems).
        const size_t PBQ = (size_t)Bv * Hv * Sv * HD;  // 8,388,608
        unsigned short* qb = wsp;
        unsigned short* kb = qb + PBQ;
        unsigned short* vb = kb + PBQ;
        unsigned short* ab = vb + PBQ;
        unsigned short* wt_kb = kb;                    // kb dead until K-GEMM
        unsigned short* wt_out = (unsigned short*)d_out;  // d_out dead until end
        unsigned short* wt_vb = vb;                    // vb dead after attn

        const int M = Bv * Sv;
        dim3 gg(8, M / 128), gc(M * 1024 / 2048);

        // V path: cvt(value)->ab ; V-GEMM ab->qb(temp) ; transpose qb->vb
        cvt_bf16<<<gc, bb, 0, stream>>>(value, ab);
        transpose_w<<<gt, bb, 0, stream>>>(wv, wt_kb);
        gemm_mfma<1><<<gg, bb, 0, stream>>>(ab, wt_kb, bv, qb, M, 1024, 1024);
        transpose_v<<<dim3(Sv / 64, Bv * Hv), bb, 0, stream>>>(qb, vb);

        // Q path (kb still dead)
        cvt_bf16<<<gc, bb, 0, stream>>>(query, ab);
        transpose_w<<<gt, bb, 0, stream>>>(wq, wt_kb);
        gemm_mfma<1><<<gg, bb, 0, stream>>>(ab, wt_kb, bq, qb, M, 1024, 1024);

        // K path (W^T scratch in d_out; kb is the GEMM target now)
        cvt_bf16<<<gc, bb, 0, stream>>>(key, ab);
        transpose_w<<<gt, bb, 0, stream>>>(wk, wt_out);
        gemm_mfma<1><<<gg, bb, 0, stream>>>(ab, wt_out, bk, kb, M, 1024, 1024);

        // Attention -> ab
        attn_mfma<<<dim3(Sv / 128, Hv, Bv), bb, 0, stream>>>(qb, kb, vb, amask, ab);

        // Output projection (W^T in dead vb; writes every element of d_out)
        transpose_w<<<gt, bb, 0, stream>>>(wo, wt_vb);
        gemm_mfma<0><<<gg, bb, 0, stream>>>(ab, wt_vb, bo, out, M, 1024, 1024);
    } else {
        // Per-batch fallback: qb|kb|vb|ab at 4 MB each = 16 MB.
        const size_t PQ = (size_t)Hv * Sv * HD;  // 2,097,152
        unsigned short* qb = wsp;
        unsigned short* kb = qb + PQ;
        unsigned short* vb = kb + PQ;
        unsigned short* ab = vb + PQ;
        const int M = Sv;
        dim3 gg(8, M / 128), gc(M * 1024 / 2048);
        for (int b = 0; b < Bv; ++b) {
            const size_t xoff = (size_t)b * Sv * Dv;
            unsigned short* wt_kb = kb;
            unsigned short* wt_out = (unsigned short*)(out + xoff);
            unsigned short* wt_vb = vb;

            cvt_bf16<<<gc, bb, 0, stream>>>(value + xoff, ab);
            transpose_w<<<gt, bb, 0, stream>>>(wv, wt_kb);
            gemm_mfma<1><<<gg, bb, 0, stream>>>(ab, wt_kb, bv, qb, M, 1024, 1024);
            transpose_v<<<dim3(Sv / 64, Hv), bb, 0, stream>>>(qb, vb);

            cvt_bf16<<<gc, bb, 0, stream>>>(query + xoff, ab);
            transpose_w<<<gt, bb, 0, stream>>>(wq, wt_kb);
            gemm_mfma<1><<<gg, bb, 0, stream>>>(ab, wt_kb, bq, qb, M, 1024, 1024);

            cvt_bf16<<<gc, bb, 0, stream>>>(key + xoff, ab);
            transpose_w<<<gt, bb, 0, stream>>>(wk, wt_out);
            gemm_mfma<1><<<gg, bb, 0, stream>>>(ab, wt_out, bk, kb, M, 1024, 1024);

            attn_mfma<<<dim3(Sv / 128, Hv, 1), bb, 0, stream>>>(qb, kb, vb,
                                                                amask + (size_t)b * Sv, ab);

            transpose_w<<<gt, bb, 0, stream>>>(wo, wt_vb);
            gemm_mfma<0><<<gg, bb, 0, stream>>>(ab, wt_vb, bo, out + xoff, M, 1024, 1024);
        }
    }
}